// Round 10
// baseline (107.699 us; speedup 1.0000x reference)
//
#include <hip/hip_runtime.h>
#include <hip/hip_bf16.h>
#include <stdint.h>

// Problem constants
#define B_ 32
#define L_ 512
#define I_ 1024
#define O_ 1024
#define NKT 16            // K-tiles of BK=64

typedef float  f32x4  __attribute__((ext_vector_type(4)));
typedef __bf16 bf16x4 __attribute__((ext_vector_type(4)));
typedef __bf16 bf16x8 __attribute__((ext_vector_type(8)));

#define CFENCE() asm volatile("" ::: "memory")
#define BARRIER() do { CFENCE(); __builtin_amdgcn_s_barrier(); CFENCE(); } while (0)

// ---- async global->LDS, 16B per lane (global_load_lds_dwordx4) ----
__device__ __forceinline__ void gload_lds16(const void* g, void* l) {
    __builtin_amdgcn_global_load_lds(
        (const __attribute__((address_space(1))) uint32_t*)(uintptr_t)g,
        (__attribute__((address_space(3))) uint32_t*)(uint32_t)(uintptr_t)l,
        16, 0, 0);
}

// ============================ Pass 1a: W = mean + eps * exp(0.5*lv) ============================
// Branchless grid-stride (R2/R5-proven ~6.2 TB/s). Do NOT merge with cvt_x (R4 regression).
__global__ void gen_w_kernel(const float* __restrict__ wmean,
                             const float* __restrict__ wlv,
                             const float* __restrict__ noise,
                             __bf16* __restrict__ W)
{
    const int n4 = B_ * O_ * I_ / 4;
    const int stride = gridDim.x * blockDim.x;
    for (int i = blockIdx.x * blockDim.x + threadIdx.x; i < n4; i += stride) {
        const int mi = i & (O_ * I_ / 4 - 1);
        const f32x4 m4 = *(const f32x4*)(wmean + (size_t)mi * 4);
        const f32x4 l4 = *(const f32x4*)(wlv   + (size_t)mi * 4);
        const f32x4 e4 = *(const f32x4*)(noise + (size_t)i  * 4);
        bf16x4 w;
        w[0] = (__bf16)(m4[0] + e4[0] * __expf(0.5f * l4[0]));
        w[1] = (__bf16)(m4[1] + e4[1] * __expf(0.5f * l4[1]));
        w[2] = (__bf16)(m4[2] + e4[2] * __expf(0.5f * l4[2]));
        w[3] = (__bf16)(m4[3] + e4[3] * __expf(0.5f * l4[3]));
        *(bf16x4*)(W + (size_t)i * 4) = w;
    }
}

// ============================ Pass 1b: x -> bf16 ============================
__global__ void cvt_x_kernel(const float* __restrict__ x, __bf16* __restrict__ xb)
{
    const int n4 = B_ * L_ * I_ / 4;
    const int stride = gridDim.x * blockDim.x;
    for (int i = blockIdx.x * blockDim.x + threadIdx.x; i < n4; i += stride) {
        const f32x4 v = *(const f32x4*)(x + (size_t)i * 4);
        bf16x4 w;
        w[0] = (__bf16)v[0]; w[1] = (__bf16)v[1];
        w[2] = (__bf16)v[2]; w[3] = (__bf16)v[3];
        *(bf16x4*)(xb + (size_t)i * 4) = w;
    }
}

// ============================ Pass 2: 256x256 8-wave GEMM, m201 8-phase schedule ============================
// R10 change (THE m201-faithful phase skeleton): per phase
//   { ds_read frags ; STG ; barrier ; setprio(1) MFMA setprio(0) ; barrier }
// Reads are issued BEFORE the barrier and consumed AFTER it -> ds_read latency and the
// 8-wave LDS-pipe backlog complete during the barrier wait; the compiler's auto lgkmcnt
// before the first MFMA is then ~free. R8/R9 had reads AFTER the barrier in the same
// segment as MFMA -> every phase serially paid the full LDS drain (~9000 cyc/K-tile vs
// m201's 3300). Staging positions + vmcnt(4)-per-tile identical to R8 (audited safe:
// B(t+2) overwrite is >=3 barriers after all waves' P0 B-reads of tile t).
__global__ __launch_bounds__(512, 2) void gemm_8ph(const __bf16* __restrict__ xb,
                                                   const __bf16* __restrict__ W,
                                                   const float* __restrict__ bias,
                                                   float* __restrict__ out)
{
    __shared__ __align__(16) char smem[131072];
    // K-loop: A halftile slot (d,h): (d*2+h)*16384 ; B halftile slot: 65536 + (d*2+h)*16384
    // Epilogue: reused as [64][260] f32 per round.

    // 256 blocks, XCD swizzle (256%8==0): 32 consecutive logical blocks per XCD = 4 whole batches.
    const int bid = ((int)blockIdx.x & 7) * 32 + ((int)blockIdx.x >> 3);
    const int b   = bid >> 3;
    const int mt  = (bid >> 2) & 1;
    const int nt  = bid & 3;

    const int tid  = threadIdx.x;
    const int wid  = tid >> 6, lane = tid & 63;
    const int wr   = wid >> 2;         // 0..1 (M)
    const int wc   = wid & 3;          // 0..3 (N)
    const int hr   = lane & 15;
    const int kq   = lane >> 4;

    // ---- staging geometry: thread covers phys 16B chunks tid and tid+512 of a half-tile ----
    const int P0c = tid, P1c = tid + 512;
    const int r0 = P0c >> 3, c0 = (P0c & 7) ^ (r0 & 7);   // pre-swizzled global col chunk
    const int r1 = P1c >> 3, c1 = (P1c & 7) ^ (r1 & 7);
    const size_t gO0 = (size_t)r0 * I_ + c0 * 8;
    const size_t gO1 = (size_t)r1 * I_ + c1 * 8;

    const __bf16* ax = xb + (size_t)b * L_ * I_ + (size_t)(mt * 256) * I_;
    const __bf16* bw = W  + (size_t)b * O_ * I_ + (size_t)(nt * 256) * I_;

#define STG(srcp, slotbyte) do {                                          \
        gload_lds16((srcp) + gO0, smem + (slotbyte) + tid * 16);          \
        gload_lds16((srcp) + gO1, smem + (slotbyte) + 8192 + tid * 16);   \
    } while (0)

    // ---- ds_read fragment addressing (swizzled chunk: phys = logical ^ (row&7)) ----
    const int pc0 = (0 + kq) ^ (hr & 7);          // kk=0 chunk
    const int pc1 = (4 + kq) ^ (hr & 7);          // kk=1 chunk
    const int aob = wr * 16384 + hr * 128;                        // region-relative
    const int bob = (wc >> 1) * 16384 + (wc & 1) * 8192 + hr * 128;  // region-relative

    f32x4 acc[8][4];
    #pragma unroll
    for (int m = 0; m < 8; ++m)
        #pragma unroll
        for (int n = 0; n < 4; ++n)
            acc[m][n] = (f32x4)(0.0f);

#define LDA(mb, dA_) do {                                                             \
        _Pragma("unroll")                                                             \
        for (int mm = 0; mm < 2; ++mm) {                                              \
            af[mm][0] = *(const bf16x8*)(smem + (dA_) + aob + ((mb)+mm)*2048 + pc0*16); \
            af[mm][1] = *(const bf16x8*)(smem + (dA_) + aob + ((mb)+mm)*2048 + pc1*16); \
        } } while (0)

#define DO_MFMA(mb) do {                                                              \
        __builtin_amdgcn_s_setprio(1);                                                \
        _Pragma("unroll")                                                             \
        for (int mm = 0; mm < 2; ++mm)                                                \
            _Pragma("unroll")                                                         \
            for (int n = 0; n < 4; ++n)                                               \
                _Pragma("unroll")                                                     \
                for (int kk = 0; kk < 2; ++kk)                                        \
                    acc[(mb)+mm][n] = __builtin_amdgcn_mfma_f32_16x16x32_bf16(        \
                        af[mm][kk], bfr[n][kk], acc[(mb)+mm][n], 0, 0, 0);            \
        __builtin_amdgcn_s_setprio(0); } while (0)

    // ---- prologue: stage B(0), A(0), B(1); wait tile-0 resident (last 2 stages in flight) ----
    STG(bw,                         65536 + 0);
    STG(bw + (size_t)128 * I_,      65536 + 16384);
    STG(ax,                         0);
    STG(ax + (size_t)128 * I_,      16384);
    STG(bw + 64,                    65536 + 32768);
    STG(bw + (size_t)128 * I_ + 64, 65536 + 32768 + 16384);
    CFENCE(); asm volatile("s_waitcnt vmcnt(4)" ::: "memory");
    BARRIER();

    for (int t = 0; t < NKT; ++t) {
        const int d  = t & 1;
        const int dA = d * 32768;
        const int dB = 65536 + d * 32768;
        const int dN = (d ^ 1) * 32768;     // A dbuf for tile t+1
        bf16x8 af[2][2], bfr[4][2];

        // ---- P0: read all B frags + A m01 ; stage Ah0(t+1) ; barrier ; MFMA m01 ----
        #pragma unroll
        for (int n = 0; n < 4; ++n) {
            bfr[n][0] = *(const bf16x8*)(smem + dB + bob + n * 2048 + pc0 * 16);
            bfr[n][1] = *(const bf16x8*)(smem + dB + bob + n * 2048 + pc1 * 16);
        }
        LDA(0, dA);
        if (t + 1 < NKT) STG(ax + (size_t)(t + 1) * 64, dN);
        BARRIER();
        DO_MFMA(0);
        BARRIER();

        // ---- P1: read A m23 ; stage Ah1(t+1) ; barrier ; MFMA m23 ----
        LDA(2, dA);
        if (t + 1 < NKT) STG(ax + (size_t)128 * I_ + (size_t)(t + 1) * 64, dN + 16384);
        BARRIER();
        DO_MFMA(2);
        BARRIER();

        // ---- P2: read A m45 ; stage Bh0(t+2) (tile t's B fully read at P0) ; barrier ; MFMA m45 ----
        LDA(4, dA);
        if (t + 2 < NKT) STG(bw + (size_t)(t + 2) * 64, dB);
        BARRIER();
        DO_MFMA(4);
        BARRIER();

        // ---- P3: read A m67 ; stage Bh1(t+2) ; counted vmcnt ; barrier ; MFMA m67 ----
        LDA(6, dA);
        if (t + 2 < NKT) STG(bw + (size_t)128 * I_ + (size_t)(t + 2) * 64, dB + 16384);
        if (t < NKT - 2)       { CFENCE(); asm volatile("s_waitcnt vmcnt(4)" ::: "memory"); }
        else if (t == NKT - 2) { CFENCE(); asm volatile("s_waitcnt vmcnt(0)" ::: "memory"); }
        BARRIER();
        DO_MFMA(6);
        BARRIER();
    }
#undef STG
#undef LDA
#undef DO_MFMA

    // ================= Epilogue (R9): LDS transpose -> coalesced full-row stores =================
    // 4 rounds over 64-row slabs. Round r: rows mt*256 + r*64 .. +63, owned by waves with
    // wr == r>>1, acc m = (r&1)*4 + mm. LDS slab [64][260] f32 (pad kills write conflicts).
    // Store phase: each wave-instr writes ONE full 1KB row (64 lanes x float4, contiguous).
    {
        float* eb = (float*)smem;
        const f32x4 bias4 = *(const f32x4*)(bias + nt * 256 + lane * 4);  // per-lane cols, all rows
        float* ob = out + ((size_t)b * L_ + (size_t)(mt * 256)) * O_ + nt * 256;
        #pragma unroll
        for (int r = 0; r < 4; ++r) {
            BARRIER();   // previous round's LDS reads done (r=0: K-loop tail barrier already done, harmless)
            if (wr == (r >> 1)) {
                #pragma unroll
                for (int mm = 0; mm < 4; ++mm)
                    #pragma unroll
                    for (int n = 0; n < 4; ++n) {
                        const int col = wc * 64 + n * 16 + hr;
                        #pragma unroll
                        for (int j = 0; j < 4; ++j)
                            eb[(mm * 16 + kq * 4 + j) * 260 + col] = acc[(r & 1) * 4 + mm][n][j];
                    }
            }
            BARRIER();   // publish slab
            #pragma unroll
            for (int rr = 0; rr < 8; ++rr) {
                const int row = wid * 8 + rr;              // 0..63 within slab
                f32x4 v = *(const f32x4*)&eb[row * 260 + lane * 4];
                v += bias4;
                *(f32x4*)&ob[(size_t)(r * 64 + row) * O_ + lane * 4] = v;
            }
        }
    }
}

// ============================ Fallback (no workspace): R1 fused kernel ============================
#define LDSPAD 40
__global__ void bayes_gemm_fused(const float* __restrict__ x,
                                 const float* __restrict__ wmean,
                                 const float* __restrict__ wlogvar,
                                 const float* __restrict__ bias,
                                 const float* __restrict__ noise,
                                 float* __restrict__ out)
{
    __shared__ __bf16 As[128 * LDSPAD];
    __shared__ __bf16 Bs[128 * LDSPAD];
    const int bid  = blockIdx.x;
    const int b    = bid >> 5;
    const int mt   = (bid >> 3) & 3;
    const int nt   = bid & 7;
    const int t    = threadIdx.x;
    const int wave = t >> 6, lane = t & 63;
    const int wr   = wave >> 1, wc = wave & 1;
    const int hr   = lane & 15, kq = lane >> 4;
    const float* xb = x     + (size_t)b * L_ * I_;
    const float* nb = noise + (size_t)b * O_ * I_;
    f32x4 acc[4][4];
    #pragma unroll
    for (int m = 0; m < 4; ++m)
        #pragma unroll
        for (int n = 0; n < 4; ++n) acc[m][n] = (f32x4)(0.0f);
    for (int k0 = 0; k0 < I_; k0 += 32) {
        #pragma unroll
        for (int j = 0; j < 4; ++j) {
            const int s = t + j * 256, row = s >> 3, q = s & 7;
            const float4 v = *(const float4*)(xb + (size_t)(mt * 128 + row) * I_ + k0 + q * 4);
            __bf16* dst = &As[row * LDSPAD + q * 4];
            dst[0] = (__bf16)v.x; dst[1] = (__bf16)v.y; dst[2] = (__bf16)v.z; dst[3] = (__bf16)v.w;
        }
        #pragma unroll
        for (int j = 0; j < 4; ++j) {
            const int s = t + j * 256, row = s >> 3, q = s & 7;
            const size_t off = (size_t)(nt * 128 + row) * I_ + k0 + q * 4;
            const float4 m4 = *(const float4*)(wmean + off);
            const float4 l4 = *(const float4*)(wlogvar + off);
            const float4 n4 = *(const float4*)(nb + off);
            __bf16* dst = &Bs[row * LDSPAD + q * 4];
            dst[0] = (__bf16)(m4.x + n4.x * __expf(0.5f * l4.x));
            dst[1] = (__bf16)(m4.y + n4.y * __expf(0.5f * l4.y));
            dst[2] = (__bf16)(m4.z + n4.z * __expf(0.5f * l4.z));
            dst[3] = (__bf16)(m4.w + n4.w * __expf(0.5f * l4.w));
        }
        __syncthreads();
        bf16x8 af[4], bfr[4];
        #pragma unroll
        for (int m = 0; m < 4; ++m)
            af[m] = *(const bf16x8*)&As[(wr * 64 + m * 16 + hr) * LDSPAD + kq * 8];
        #pragma unroll
        for (int n = 0; n < 4; ++n)
            bfr[n] = *(const bf16x8*)&Bs[(wc * 64 + n * 16 + hr) * LDSPAD + kq * 8];
        #pragma unroll
        for (int m = 0; m < 4; ++m)
            #pragma unroll
            for (int n = 0; n < 4; ++n)
                acc[m][n] = __builtin_amdgcn_mfma_f32_16x16x32_bf16(af[m], bfr[n], acc[m][n], 0, 0, 0);
        __syncthreads();
    }
    float* ob = out + (size_t)b * L_ * O_;
    #pragma unroll
    for (int n = 0; n < 4; ++n) {
        const int col = nt * 128 + wc * 64 + n * 16 + hr;
        const float bv = bias[col];
        #pragma unroll
        for (int m = 0; m < 4; ++m) {
            const int row0 = mt * 128 + wr * 64 + m * 16 + kq * 4;
            #pragma unroll
            for (int j = 0; j < 4; ++j)
                ob[(size_t)(row0 + j) * O_ + col] = acc[m][n][j] + bv;
        }
    }
}

extern "C" void kernel_launch(void* const* d_in, const int* in_sizes, int n_in,
                              void* d_out, int out_size, void* d_ws, size_t ws_size,
                              hipStream_t stream) {
    const float* x       = (const float*)d_in[0];
    const float* wmean   = (const float*)d_in[1];
    const float* wlogvar = (const float*)d_in[2];
    const float* bias    = (const float*)d_in[3];
    const float* noise   = (const float*)d_in[4];
    float* out           = (float*)d_out;

    const size_t w_bytes  = (size_t)B_ * O_ * I_ * 2;   // 64 MiB
    const size_t xb_bytes = (size_t)B_ * L_ * I_ * 2;   // 32 MiB

    if (ws_size >= w_bytes + xb_bytes) {
        __bf16* W    = (__bf16*)d_ws;
        __bf16* xbuf = (__bf16*)((char*)d_ws + w_bytes);
        gen_w_kernel<<<dim3(2048), dim3(256), 0, stream>>>(wmean, wlogvar, noise, W);
        cvt_x_kernel<<<dim3(1024), dim3(256), 0, stream>>>(x, xbuf);
        gemm_8ph<<<dim3(256), dim3(512), 0, stream>>>(xbuf, W, bias, out);
    } else {
        bayes_gemm_fused<<<dim3(1024), dim3(256), 0, stream>>>(
            x, wmean, wlogvar, bias, noise, out);
    }
}

// Round 11
// 99.957 us; speedup vs baseline: 1.0774x; 1.0774x over previous
//
#include <hip/hip_runtime.h>
#include <hip/hip_bf16.h>
#include <stdint.h>

// Problem constants
#define B_ 32
#define L_ 512
#define I_ 1024
#define O_ 1024
#define NKT 16            // K-tiles of BK=64

typedef float  f32x4  __attribute__((ext_vector_type(4)));
typedef __bf16 bf16x4 __attribute__((ext_vector_type(4)));
typedef __bf16 bf16x8 __attribute__((ext_vector_type(8)));

#define CFENCE() asm volatile("" ::: "memory")
#define BARRIER() do { CFENCE(); __builtin_amdgcn_s_barrier(); CFENCE(); } while (0)
#define LGKM0()  asm volatile("s_waitcnt lgkmcnt(0)" ::: "memory")

// ============================ Pass 0: mean,logvar f32 -> mean bf16, sigma bf16 ============================
// 4 MiB ws; sigma = exp(0.5*lv). Kills exp + f32 mean/lv loads in the GEMM's B-staging.
// Precision: sigma in [9e-4, 0.018], bf16 rel err 0.4% -> W-term error << bf16(W) rounding.
__global__ void gen_ms_kernel(const float* __restrict__ wmean, const float* __restrict__ wlv,
                              __bf16* __restrict__ mz, __bf16* __restrict__ sg)
{
    const int i = blockIdx.x * blockDim.x + threadIdx.x;   // exactly O*I/4 threads
    const f32x4 m = *(const f32x4*)(wmean + (size_t)i * 4);
    const f32x4 l = *(const f32x4*)(wlv   + (size_t)i * 4);
    bf16x4 mb, sb;
    #pragma unroll
    for (int e = 0; e < 4; ++e) {
        mb[e] = (__bf16)m[e];
        sb[e] = (__bf16)__expf(0.5f * l[e]);
    }
    *(bf16x4*)(mz + (size_t)i * 4) = mb;
    *(bf16x4*)(sg + (size_t)i * 4) = sb;
}

// ============================ Fused 256x256 8-wave GEMM: W built during B-staging ============================
// C[b](512x1024) = X[b] * (mean + noise[b]*sigma)^T + bias.  BM=BN=256, BK=64,
// 8 waves (2M x 4N), per-wave 128x64 out.  LDS 128 KB: A[2dbuf][2half][16KB] + B same.
// Reg-staged (T14): per tile t -> t+1: issue Bh0@P0, write@P1; issue Bh1@P1, write@P2;
// issue A@P2, write@P3. Compiler inserts exact counted vmcnt for the reg deps.
// ds_write swizzle: phys chunk = logical ^ (row&7) (write-side; read side identical to R8-R10).
// LGKM0 before barrier after ds_writes = cross-wave visibility (compiler can't know).
__global__ __launch_bounds__(512, 2) void fused_gemm(const float* __restrict__ x,
                                                     const float* __restrict__ noise,
                                                     const __bf16* __restrict__ mz,
                                                     const __bf16* __restrict__ sg,
                                                     const float* __restrict__ bias,
                                                     float* __restrict__ out)
{
    __shared__ __align__(16) char smem[131072];
    // A halftile slot (d,h): (d*2+h)*16384 ; B halftile slot: 65536 + (d*2+h)*16384

    const int bid = ((int)blockIdx.x & 7) * 32 + ((int)blockIdx.x >> 3);  // XCD swizzle, 256%8==0
    const int b   = bid >> 3;
    const int mt  = (bid >> 2) & 1;
    const int nt  = bid & 3;

    const int tid  = threadIdx.x;
    const int wid  = tid >> 6, lane = tid & 63;
    const int wr   = wid >> 2;         // 0..1 (M)
    const int wc   = wid & 3;          // 0..3 (N)
    const int hr   = lane & 15;
    const int kq   = lane >> 4;

    // ---- staging geometry: thread owns LOGICAL 16B chunks (r0,c0) and (r0+64,c0) of each halftile ----
    const int r0 = tid >> 3, c0 = tid & 7;
    const size_t gOa = (size_t)r0 * I_ + c0 * 8;          // element offset (same for f32/bf16 arrays)
    const size_t gOb = gOa + (size_t)64 * I_;
    const int wba = r0 * 128 + ((c0 ^ (r0 & 7)) * 16);    // swizzled LDS byte (chunk a); chunk b = +8192
    #define HOFW ((size_t)128 * I_)                        // halftile-1 row offset (elements)

    const float*  axB = x     + ((size_t)b * L_ + mt * 256) * I_;
    const float*  nzB = noise + ((size_t)b * O_ + nt * 256) * I_;
    const __bf16* mzB = mz    + (size_t)(nt * 256) * I_;
    const __bf16* sgB = sg    + (size_t)(nt * 256) * I_;

    // ---- staged registers (live across phase barriers) ----
    bf16x8 sBm0, sBm1, sBs0, sBs1;
    f32x4  sBn00, sBn01, sBn10, sBn11;
    f32x4  sA00, sA01, sA02, sA03, sA10, sA11, sA12, sA13;

#define B_ISSUE(hko) do {                                                  \
        sBm0  = *(const bf16x8*)(mzB + (hko) + gOa);                       \
        sBm1  = *(const bf16x8*)(mzB + (hko) + gOb);                       \
        sBs0  = *(const bf16x8*)(sgB + (hko) + gOa);                       \
        sBs1  = *(const bf16x8*)(sgB + (hko) + gOb);                       \
        sBn00 = *(const f32x4*)(nzB + (hko) + gOa);                        \
        sBn01 = *(const f32x4*)(nzB + (hko) + gOa + 4);                    \
        sBn10 = *(const f32x4*)(nzB + (hko) + gOb);                        \
        sBn11 = *(const f32x4*)(nzB + (hko) + gOb + 4);                    \
    } while (0)

#define B_WRITE(slot) do {                                                 \
        bf16x8 w0_, w1_;                                                   \
        _Pragma("unroll")                                                  \
        for (int e = 0; e < 4; ++e) {                                      \
            w0_[e]   = (__bf16)((float)sBm0[e]   + sBn00[e] * (float)sBs0[e]);   \
            w0_[e+4] = (__bf16)((float)sBm0[e+4] + sBn01[e] * (float)sBs0[e+4]); \
            w1_[e]   = (__bf16)((float)sBm1[e]   + sBn10[e] * (float)sBs1[e]);   \
            w1_[e+4] = (__bf16)((float)sBm1[e+4] + sBn11[e] * (float)sBs1[e+4]); \
        }                                                                  \
        *(bf16x8*)(smem + (slot) + wba)        = w0_;                      \
        *(bf16x8*)(smem + (slot) + wba + 8192) = w1_;                      \
    } while (0)

#define A_ISSUE(ko_) do {                                                  \
        sA00 = *(const f32x4*)(axB + (ko_) + gOa);                         \
        sA01 = *(const f32x4*)(axB + (ko_) + gOa + 4);                     \
        sA02 = *(const f32x4*)(axB + (ko_) + gOb);                         \
        sA03 = *(const f32x4*)(axB + (ko_) + gOb + 4);                     \
        sA10 = *(const f32x4*)(axB + (ko_) + HOFW + gOa);                  \
        sA11 = *(const f32x4*)(axB + (ko_) + HOFW + gOa + 4);              \
        sA12 = *(const f32x4*)(axB + (ko_) + HOFW + gOb);                  \
        sA13 = *(const f32x4*)(axB + (ko_) + HOFW + gOb + 4);              \
    } while (0)

#define A_WRITE(dw) do {                                                   \
        bf16x8 a0_, a1_, a2_, a3_;                                         \
        _Pragma("unroll")                                                  \
        for (int e = 0; e < 4; ++e) {                                      \
            a0_[e] = (__bf16)sA00[e]; a0_[e+4] = (__bf16)sA01[e];          \
            a1_[e] = (__bf16)sA02[e]; a1_[e+4] = (__bf16)sA03[e];          \
            a2_[e] = (__bf16)sA10[e]; a2_[e+4] = (__bf16)sA11[e];          \
            a3_[e] = (__bf16)sA12[e]; a3_[e+4] = (__bf16)sA13[e];          \
        }                                                                  \
        *(bf16x8*)(smem + (dw) + wba)                = a0_;                \
        *(bf16x8*)(smem + (dw) + wba + 8192)         = a1_;                \
        *(bf16x8*)(smem + (dw) + 16384 + wba)        = a2_;                \
        *(bf16x8*)(smem + (dw) + 16384 + wba + 8192) = a3_;                \
    } while (0)

    // ---- ds_read fragment addressing (identical to R8-R10, verified) ----
    const int pc0 = (0 + kq) ^ (hr & 7);
    const int pc1 = (4 + kq) ^ (hr & 7);
    const int aob = wr * 16384 + hr * 128;
    const int bob = (wc >> 1) * 16384 + (wc & 1) * 8192 + hr * 128;

    f32x4 acc[8][4];
    #pragma unroll
    for (int m = 0; m < 8; ++m)
        #pragma unroll
        for (int n = 0; n < 4; ++n)
            acc[m][n] = (f32x4)(0.0f);

#define LDA(mb, dA_) do {                                                             \
        _Pragma("unroll")                                                             \
        for (int mm = 0; mm < 2; ++mm) {                                              \
            af[mm][0] = *(const bf16x8*)(smem + (dA_) + aob + ((mb)+mm)*2048 + pc0*16); \
            af[mm][1] = *(const bf16x8*)(smem + (dA_) + aob + ((mb)+mm)*2048 + pc1*16); \
        } } while (0)

#define DO_MFMA(mb) do {                                                              \
        __builtin_amdgcn_s_setprio(1);                                                \
        _Pragma("unroll")                                                             \
        for (int mm = 0; mm < 2; ++mm)                                                \
            _Pragma("unroll")                                                         \
            for (int n = 0; n < 4; ++n)                                               \
                _Pragma("unroll")                                                     \
                for (int kk = 0; kk < 2; ++kk)                                        \
                    acc[(mb)+mm][n] = __builtin_amdgcn_mfma_f32_16x16x32_bf16(        \
                        af[mm][kk], bfr[n][kk], acc[(mb)+mm][n], 0, 0, 0);            \
        __builtin_amdgcn_s_setprio(0); } while (0)

    // ---- prologue: build tile 0 into buf 0 (reg-staged, sequential; one-time) ----
    B_ISSUE(0);            B_WRITE(65536 + 0);
    B_ISSUE(HOFW);         B_WRITE(65536 + 16384);
    A_ISSUE(0);            A_WRITE(0);
    LGKM0();
    BARRIER();

    for (int t = 0; t < NKT; ++t) {
        const int d   = t & 1;
        const int dA  = d * 32768;
        const int dB  = 65536 + d * 32768;
        const int w32 = (d ^ 1) * 32768;       // dbuf for tile t+1
        const bool stg = (t + 1 < NKT);
        const size_t kon = (size_t)(t + 1) * 64;
        bf16x8 af[2][2], bfr[4][2];

        // ---- P0: read all B frags + A m01 ; issue Bh0(t+1) ----
        #pragma unroll
        for (int n = 0; n < 4; ++n) {
            bfr[n][0] = *(const bf16x8*)(smem + dB + bob + n * 2048 + pc0 * 16);
            bfr[n][1] = *(const bf16x8*)(smem + dB + bob + n * 2048 + pc1 * 16);
        }
        LDA(0, dA);
        if (stg) B_ISSUE(kon);
        BARRIER();
        DO_MFMA(0);
        BARRIER();

        // ---- P1: read A m23 ; write Bh0 ; issue Bh1 ----
        LDA(2, dA);
        if (stg) { B_WRITE(65536 + w32); B_ISSUE(HOFW + kon); LGKM0(); }
        BARRIER();
        DO_MFMA(2);
        BARRIER();

        // ---- P2: read A m45 ; issue A(t+1) ; write Bh1 ----
        LDA(4, dA);
        if (stg) { A_ISSUE(kon); B_WRITE(65536 + w32 + 16384); LGKM0(); }
        BARRIER();
        DO_MFMA(4);
        BARRIER();

        // ---- P3: read A m67 ; write A(t+1) ----
        LDA(6, dA);
        if (stg) { A_WRITE(w32); LGKM0(); }
        BARRIER();
        DO_MFMA(6);
        BARRIER();
    }
#undef B_ISSUE
#undef B_WRITE
#undef A_ISSUE
#undef A_WRITE
#undef LDA
#undef DO_MFMA

    // ================= Epilogue (R9, verified): LDS transpose -> coalesced full-row stores =================
    {
        float* eb = (float*)smem;
        const f32x4 bias4 = *(const f32x4*)(bias + nt * 256 + lane * 4);
        float* ob = out + ((size_t)b * L_ + (size_t)(mt * 256)) * O_ + nt * 256;
        #pragma unroll
        for (int r = 0; r < 4; ++r) {
            BARRIER();
            if (wr == (r >> 1)) {
                #pragma unroll
                for (int mm = 0; mm < 4; ++mm)
                    #pragma unroll
                    for (int n = 0; n < 4; ++n) {
                        const int col = wc * 64 + n * 16 + hr;
                        #pragma unroll
                        for (int j = 0; j < 4; ++j)
                            eb[(mm * 16 + kq * 4 + j) * 260 + col] = acc[(r & 1) * 4 + mm][n][j];
                    }
            }
            BARRIER();
            #pragma unroll
            for (int rr = 0; rr < 8; ++rr) {
                const int row = wid * 8 + rr;
                f32x4 v = *(const f32x4*)&eb[row * 260 + lane * 4];
                v += bias4;
                *(f32x4*)&ob[(size_t)(r * 64 + row) * O_ + lane * 4] = v;
            }
        }
    }
}

// ============================ Fallback (no workspace): R1 fused kernel ============================
#define LDSPAD 40
__global__ void bayes_gemm_fused(const float* __restrict__ x,
                                 const float* __restrict__ wmean,
                                 const float* __restrict__ wlogvar,
                                 const float* __restrict__ bias,
                                 const float* __restrict__ noise,
                                 float* __restrict__ out)
{
    __shared__ __bf16 As[128 * LDSPAD];
    __shared__ __bf16 Bs[128 * LDSPAD];
    const int bid  = blockIdx.x;
    const int b    = bid >> 5;
    const int mt   = (bid >> 3) & 3;
    const int nt   = bid & 7;
    const int t    = threadIdx.x;
    const int wave = t >> 6, lane = t & 63;
    const int wr   = wave >> 1, wc = wave & 1;
    const int hr   = lane & 15, kq = lane >> 4;
    const float* xb = x     + (size_t)b * L_ * I_;
    const float* nb = noise + (size_t)b * O_ * I_;
    f32x4 acc[4][4];
    #pragma unroll
    for (int m = 0; m < 4; ++m)
        #pragma unroll
        for (int n = 0; n < 4; ++n) acc[m][n] = (f32x4)(0.0f);
    for (int k0 = 0; k0 < I_; k0 += 32) {
        #pragma unroll
        for (int j = 0; j < 4; ++j) {
            const int s = t + j * 256, row = s >> 3, q = s & 7;
            const float4 v = *(const float4*)(xb + (size_t)(mt * 128 + row) * I_ + k0 + q * 4);
            __bf16* dst = &As[row * LDSPAD + q * 4];
            dst[0] = (__bf16)v.x; dst[1] = (__bf16)v.y; dst[2] = (__bf16)v.z; dst[3] = (__bf16)v.w;
        }
        #pragma unroll
        for (int j = 0; j < 4; ++j) {
            const int s = t + j * 256, row = s >> 3, q = s & 7;
            const size_t off = (size_t)(nt * 128 + row) * I_ + k0 + q * 4;
            const float4 m4 = *(const float4*)(wmean + off);
            const float4 l4 = *(const float4*)(wlogvar + off);
            const float4 n4 = *(const float4*)(nb + off);
            __bf16* dst = &Bs[row * LDSPAD + q * 4];
            dst[0] = (__bf16)(m4.x + n4.x * __expf(0.5f * l4.x));
            dst[1] = (__bf16)(m4.y + n4.y * __expf(0.5f * l4.y));
            dst[2] = (__bf16)(m4.z + n4.z * __expf(0.5f * l4.z));
            dst[3] = (__bf16)(m4.w + n4.w * __expf(0.5f * l4.w));
        }
        __syncthreads();
        bf16x8 af[4], bfr[4];
        #pragma unroll
        for (int m = 0; m < 4; ++m)
            af[m] = *(const bf16x8*)&As[(wr * 64 + m * 16 + hr) * LDSPAD + kq * 8];
        #pragma unroll
        for (int n = 0; n < 4; ++n)
            bfr[n] = *(const bf16x8*)&Bs[(wc * 64 + n * 16 + hr) * LDSPAD + kq * 8];
        #pragma unroll
        for (int m = 0; m < 4; ++m)
            #pragma unroll
            for (int n = 0; n < 4; ++n)
                acc[m][n] = __builtin_amdgcn_mfma_f32_16x16x32_bf16(af[m], bfr[n], acc[m][n], 0, 0, 0);
        __syncthreads();
    }
    float* ob = out + (size_t)b * L_ * O_;
    #pragma unroll
    for (int n = 0; n < 4; ++n) {
        const int col = nt * 128 + wc * 64 + n * 16 + hr;
        const float bv = bias[col];
        #pragma unroll
        for (int m = 0; m < 4; ++m) {
            const int row0 = mt * 128 + wr * 64 + m * 16 + kq * 4;
            #pragma unroll
            for (int j = 0; j < 4; ++j)
                ob[(size_t)(row0 + j) * O_ + col] = acc[m][n][j] + bv;
        }
    }
}

extern "C" void kernel_launch(void* const* d_in, const int* in_sizes, int n_in,
                              void* d_out, int out_size, void* d_ws, size_t ws_size,
                              hipStream_t stream) {
    const float* x       = (const float*)d_in[0];
    const float* wmean   = (const float*)d_in[1];
    const float* wlogvar = (const float*)d_in[2];
    const float* bias    = (const float*)d_in[3];
    const float* noise   = (const float*)d_in[4];
    float* out           = (float*)d_out;

    const size_t ms_bytes = (size_t)O_ * I_ * 2 * 2;   // mean bf16 + sigma bf16 = 4 MiB

    if (ws_size >= ms_bytes) {
        __bf16* mzb = (__bf16*)d_ws;
        __bf16* sgb = mzb + (size_t)O_ * I_;
        gen_ms_kernel<<<dim3(O_ * I_ / 4 / 256), dim3(256), 0, stream>>>(wmean, wlogvar, mzb, sgb);
        fused_gemm<<<dim3(256), dim3(512), 0, stream>>>(x, noise, mzb, sgb, bias, out);
    } else {
        bayes_gemm_fused<<<dim3(1024), dim3(256), 0, stream>>>(
            x, wmean, wlogvar, bias, noise, out);
    }
}